// Round 1
// baseline (98.394 us; speedup 1.0000x reference)
//
#include <hip/hip_runtime.h>
#include <hip/hip_bf16.h>

#define NROWS 8192
#define DDIM  128
#define BM    128                 // tile rows per block side
#define NT    (NROWS / BM)        // 64 tiles per side
#define NPAIRS (NT * (NT + 1) / 2) // 2080 triangular tile pairs
#define BK    32
#define LDSB  (BK + 8)            // padded LDS row: 40 bf16 = 80 B (16B-aligned, bank-shift 20)

typedef unsigned short ushort_t;
typedef unsigned int   uint_t;
typedef __attribute__((ext_vector_type(8))) short  short8;
typedef __attribute__((ext_vector_type(4))) float  floatx4;

// round-to-nearest-even fp32 -> bf16 bits
static __device__ inline ushort_t f2bf(float f) {
    union { float f; uint_t u; } a; a.f = f;
    uint_t u = a.u + 0x7fffu + ((a.u >> 16) & 1u);
    return (ushort_t)(u >> 16);
}

// K1: row-normalize q,k (fp32) -> bf16; one wave per row. Also zero the accumulator.
__global__ __launch_bounds__(256) void norm_kernel(
    const float* __restrict__ q, const float* __restrict__ k,
    ushort_t* __restrict__ qn, ushort_t* __restrict__ kn, double* acc)
{
    if (blockIdx.x == 0 && threadIdx.x == 0) *acc = 0.0;
    int wave = threadIdx.x >> 6;
    int lane = threadIdx.x & 63;
    int row  = blockIdx.x * 4 + wave;   // grid 2048 x 4 waves = 8192 rows

    // ---- q ----
    {
        const float2* r2 = (const float2*)(q + (size_t)row * DDIM);
        float2 v = r2[lane];
        float ss = v.x * v.x + v.y * v.y;
        #pragma unroll
        for (int o = 32; o > 0; o >>= 1) ss += __shfl_xor(ss, o, 64);
        float inv = rsqrtf(fmaxf(ss, 1e-16f));
        uint_t packed = (uint_t)f2bf(v.x * inv) | ((uint_t)f2bf(v.y * inv) << 16);
        ((uint_t*)qn)[(size_t)row * 64 + lane] = packed;
    }
    // ---- k ----
    {
        const float2* r2 = (const float2*)(k + (size_t)row * DDIM);
        float2 v = r2[lane];
        float ss = v.x * v.x + v.y * v.y;
        #pragma unroll
        for (int o = 32; o > 0; o >>= 1) ss += __shfl_xor(ss, o, 64);
        float inv = rsqrtf(fmaxf(ss, 1e-16f));
        uint_t packed = (uint_t)f2bf(v.x * inv) | ((uint_t)f2bf(v.y * inv) << 16);
        ((uint_t*)kn)[(size_t)row * 64 + lane] = packed;
    }
}

// K2: for each tile pair (I<=J), compute Qs=QnI.QnJ^T and Ks=KnI.KnJ^T via MFMA,
// accumulate sum (Qs-Ks)^2 (x2 for off-diagonal tiles) into the fp64 accumulator.
__global__ __launch_bounds__(256, 2) void gram_kernel(
    const ushort_t* __restrict__ qn, const ushort_t* __restrict__ kn, double* acc)
{
    __shared__ ushort_t sQI[BM * LDSB];
    __shared__ ushort_t sQJ[BM * LDSB];
    __shared__ ushort_t sKI[BM * LDSB];
    __shared__ ushort_t sKJ[BM * LDSB];
    __shared__ float    wsum[4];

    // decode triangular pair (I <= J)
    int rem = blockIdx.x, I = 0, rowlen = NT;
    while (rem >= rowlen) { rem -= rowlen; rowlen--; I++; }
    int J = I + rem;

    int tid  = threadIdx.x;
    int wave = tid >> 6;
    int lane = tid & 63;
    int wr   = (wave >> 1) * 64;      // wave quadrant row base in 128x128 tile
    int wc   = (wave & 1) * 64;       // wave quadrant col base
    int m    = lane & 15;
    int quad = lane >> 4;

    floatx4 accQ[4][4], accK[4][4];
    #pragma unroll
    for (int a = 0; a < 4; ++a)
        #pragma unroll
        for (int b = 0; b < 4; ++b) {
            accQ[a][b] = (floatx4){0.f, 0.f, 0.f, 0.f};
            accK[a][b] = (floatx4){0.f, 0.f, 0.f, 0.f};
        }

    size_t baseI = (size_t)(I * BM) * DDIM;
    size_t baseJ = (size_t)(J * BM) * DDIM;
    int srow = tid >> 2;              // 0..63
    int scol = (tid & 3) * 8;         // ushort col offset within 32-wide slab

    #pragma unroll
    for (int kp = 0; kp < DDIM / BK; ++kp) {
        int k0 = kp * BK;
        // ---- stage 4 tiles' k-slab (128 rows x 32 bf16 each) ----
        #pragma unroll
        for (int half = 0; half < 2; ++half) {
            int r = srow + half * 64;
            size_t goff = (size_t)r * DDIM + k0 + scol;
            int loff = r * LDSB + scol;
            *(uint4*)&sQI[loff] = *(const uint4*)&qn[baseI + goff];
            *(uint4*)&sQJ[loff] = *(const uint4*)&qn[baseJ + goff];
            *(uint4*)&sKI[loff] = *(const uint4*)&kn[baseI + goff];
            *(uint4*)&sKJ[loff] = *(const uint4*)&kn[baseJ + goff];
        }
        __syncthreads();

        // ---- fragments + MFMA ----
        short8 aQ[4], aK[4], bQ[4], bK[4];
        #pragma unroll
        for (int t = 0; t < 4; ++t) {
            int ra = (wr + t * 16 + m) * LDSB + quad * 8;
            int rb = (wc + t * 16 + m) * LDSB + quad * 8;
            aQ[t] = *(const short8*)&sQI[ra];
            aK[t] = *(const short8*)&sKI[ra];
            bQ[t] = *(const short8*)&sQJ[rb];
            bK[t] = *(const short8*)&sKJ[rb];
        }
        #pragma unroll
        for (int rt = 0; rt < 4; ++rt)
            #pragma unroll
            for (int ct = 0; ct < 4; ++ct) {
                accQ[rt][ct] = __builtin_amdgcn_mfma_f32_16x16x32_bf16(aQ[rt], bQ[ct], accQ[rt][ct], 0, 0, 0);
                accK[rt][ct] = __builtin_amdgcn_mfma_f32_16x16x32_bf16(aK[rt], bK[ct], accK[rt][ct], 0, 0, 0);
            }
        __syncthreads();
    }

    // ---- epilogue: sum (diff)^2 ----
    float s = 0.f;
    #pragma unroll
    for (int rt = 0; rt < 4; ++rt)
        #pragma unroll
        for (int ct = 0; ct < 4; ++ct)
            #pragma unroll
            for (int r = 0; r < 4; ++r) {
                float d = accQ[rt][ct][r] - accK[rt][ct][r];
                s += d * d;
            }
    if (I != J) s *= 2.0f;   // symmetry: off-diagonal tile pairs counted twice

    #pragma unroll
    for (int o = 32; o > 0; o >>= 1) s += __shfl_xor(s, o, 64);
    if (lane == 0) wsum[wave] = s;
    __syncthreads();
    if (tid == 0) {
        double t = (double)wsum[0] + (double)wsum[1] + (double)wsum[2] + (double)wsum[3];
        atomicAdd(acc, t);
    }
}

// K3: scale and emit scalar
__global__ void finalize_kernel(const double* acc, float* out) {
    out[0] = (float)(*acc * (1.0 / ((double)NROWS * (double)(NROWS - 1))));
}

extern "C" void kernel_launch(void* const* d_in, const int* in_sizes, int n_in,
                              void* d_out, int out_size, void* d_ws, size_t ws_size,
                              hipStream_t stream) {
    const float* q = (const float*)d_in[0];
    const float* k = (const float*)d_in[1];
    float* out = (float*)d_out;

    double*   acc = (double*)d_ws;
    ushort_t* qn  = (ushort_t*)((char*)d_ws + 64);
    ushort_t* kn  = qn + (size_t)NROWS * DDIM;

    norm_kernel<<<NROWS / 4, 256, 0, stream>>>(q, k, qn, kn, acc);
    gram_kernel<<<NPAIRS, 256, 0, stream>>>(qn, kn, acc);
    finalize_kernel<<<1, 1, 0, stream>>>(acc, out);
}

// Round 2
// 96.149 us; speedup vs baseline: 1.0233x; 1.0233x over previous
//
#include <hip/hip_runtime.h>
#include <hip/hip_bf16.h>

#define NROWS 8192
#define DDIM  128
#define KTOT  256                  // concat K = [Qn | Kn]
#define BM    128                  // tile rows per block side
#define NT    (NROWS / BM)         // 64 tiles per side
#define NPAIRS (NT * (NT + 1) / 2) // 2080 triangular tile pairs
#define BK    64                   // bf16 per K-phase
#define NPH   (KTOT / BK)          // 4 phases
#define ROWB  (KTOT * 2)           // 512 bytes per concat row

typedef unsigned short ushort_t;
typedef unsigned int   uint_t;
typedef __attribute__((ext_vector_type(8))) short  short8;
typedef __attribute__((ext_vector_type(4))) float  floatx4;

#define LDS_PTR(p) ((__attribute__((address_space(3))) void*)(p))
#define GLB_PTR(p) ((const __attribute__((address_space(1))) void*)(p))

// round-to-nearest-even fp32 -> bf16 bits
static __device__ inline ushort_t f2bf(float f) {
    union { float f; uint_t u; } a; a.f = f;
    uint_t u = a.u + 0x7fffu + ((a.u >> 16) & 1u);
    return (ushort_t)(u >> 16);
}

// K1: row-normalize q,k -> bf16; build A=[qn|kn], B=[qn|-kn] (8192 x 256 bf16 each).
// One wave per row. Also zero the fp64 accumulator.
__global__ __launch_bounds__(256) void norm_kernel(
    const float* __restrict__ q, const float* __restrict__ k,
    uint_t* __restrict__ A, uint_t* __restrict__ B, double* acc)
{
    if (blockIdx.x == 0 && threadIdx.x == 0) *acc = 0.0;
    int wave = threadIdx.x >> 6;
    int lane = threadIdx.x & 63;
    int row  = blockIdx.x * 4 + wave;   // 2048 blocks x 4 waves = 8192 rows

    uint_t pq, pk;
    {
        const float2* r2 = (const float2*)(q + (size_t)row * DDIM);
        float2 v = r2[lane];
        float ss = v.x * v.x + v.y * v.y;
        #pragma unroll
        for (int o = 32; o > 0; o >>= 1) ss += __shfl_xor(ss, o, 64);
        float inv = rsqrtf(fmaxf(ss, 1e-16f));
        pq = (uint_t)f2bf(v.x * inv) | ((uint_t)f2bf(v.y * inv) << 16);
    }
    {
        const float2* r2 = (const float2*)(k + (size_t)row * DDIM);
        float2 v = r2[lane];
        float ss = v.x * v.x + v.y * v.y;
        #pragma unroll
        for (int o = 32; o > 0; o >>= 1) ss += __shfl_xor(ss, o, 64);
        float inv = rsqrtf(fmaxf(ss, 1e-16f));
        pk = (uint_t)f2bf(v.x * inv) | ((uint_t)f2bf(v.y * inv) << 16);
    }
    size_t rbase = (size_t)row * (KTOT / 2);   // uints per row = 128
    A[rbase + lane]      = pq;
    A[rbase + 64 + lane] = pk;
    B[rbase + lane]      = pq;
    B[rbase + 64 + lane] = pk ^ 0x80008000u;   // negate both bf16 halves
}

// K2: C = A_I . B_J^T  (= qsim - ksim) for triangular tile pairs I<=J via MFMA;
// accumulate sum C^2 (x2 off-diagonal tiles) into fp64 accumulator.
// LDS layout: unpadded 128B rows of 8 x 16B chunks, chunk XOR-swizzled by (row&7)
// so global_load_lds (wave-uniform dest) coexists with conflict-free ds_read_b128.
__global__ __launch_bounds__(256, 3) void gram_kernel(
    const ushort_t* __restrict__ A, const ushort_t* __restrict__ B, double* acc)
{
    __shared__ ushort_t sA[BM * BK];   // 16 KB
    __shared__ ushort_t sB[BM * BK];   // 16 KB
    __shared__ float    wsum[4];

    // decode triangular pair (I <= J)
    int rem = blockIdx.x, I = 0, rowlen = NT;
    while (rem >= rowlen) { rem -= rowlen; rowlen--; I++; }
    int J = I + rem;

    int tid  = threadIdx.x;
    int w    = tid >> 6;
    int l    = tid & 63;
    int m    = l & 15;
    int quad = l >> 4;
    int wr   = (w >> 1) * 64;
    int wc   = (w & 1) * 64;

    floatx4 accC[4][4];
    #pragma unroll
    for (int a = 0; a < 4; ++a)
        #pragma unroll
        for (int b = 0; b < 4; ++b)
            accC[a][b] = (floatx4){0.f, 0.f, 0.f, 0.f};

    // staging lane constants: lane l covers row (8*c + l/8) of its wave's 32-row
    // chunk, chunk (l%8) in LDS; logical chunk = (l%8) ^ (row&7)
    int lrow  = l >> 3;                       // 0..7
    int chlog = (l & 7) ^ (lrow & 7);         // wave/c-invariant per lane
    const char* gA = (const char*)A + (size_t)(I * BM) * ROWB;
    const char* gB = (const char*)B + (size_t)(J * BM) * ROWB;

    #pragma unroll
    for (int ph = 0; ph < NPH; ++ph) {
        int k0b = ph * BK * 2;   // byte offset within concat row
        #pragma unroll
        for (int c = 0; c < 4; ++c) {
            int r = w * 32 + c * 8 + lrow;    // local row 0..127
            const char* srcA = gA + (size_t)r * ROWB + k0b + chlog * 16;
            const char* srcB = gB + (size_t)r * ROWB + k0b + chlog * 16;
            __builtin_amdgcn_global_load_lds(GLB_PTR(srcA), LDS_PTR((char*)sA + (w * 4 + c) * 1024), 16, 0, 0);
            __builtin_amdgcn_global_load_lds(GLB_PTR(srcB), LDS_PTR((char*)sB + (w * 4 + c) * 1024), 16, 0, 0);
        }
        __syncthreads();

        #pragma unroll
        for (int s = 0; s < 2; ++s) {
            short8 af[4], bf[4];
            #pragma unroll
            for (int t = 0; t < 4; ++t) {
                int ra = wr + t * 16 + m;
                int rb = wc + t * 16 + m;
                int ch = (s * 4 + quad) ^ (m & 7);        // row&7 == m&7 here
                af[t] = *(const short8*)&sA[ra * 64 + ch * 8];
                bf[t] = *(const short8*)&sB[rb * 64 + ch * 8];
            }
            #pragma unroll
            for (int rt = 0; rt < 4; ++rt)
                #pragma unroll
                for (int ct = 0; ct < 4; ++ct)
                    accC[rt][ct] = __builtin_amdgcn_mfma_f32_16x16x32_bf16(af[rt], bf[ct], accC[rt][ct], 0, 0, 0);
        }
        __syncthreads();
    }

    // epilogue: sum of squares
    float s = 0.f;
    #pragma unroll
    for (int rt = 0; rt < 4; ++rt)
        #pragma unroll
        for (int ct = 0; ct < 4; ++ct)
            #pragma unroll
            for (int r = 0; r < 4; ++r) {
                float d = accC[rt][ct][r];
                s += d * d;
            }
    if (I != J) s *= 2.0f;

    #pragma unroll
    for (int o = 32; o > 0; o >>= 1) s += __shfl_xor(s, o, 64);
    if (l == 0) wsum[w] = s;
    __syncthreads();
    if (tid == 0) {
        double t = (double)wsum[0] + (double)wsum[1] + (double)wsum[2] + (double)wsum[3];
        atomicAdd(acc, t);
    }
}

// K3: scale and emit scalar
__global__ void finalize_kernel(const double* acc, float* out) {
    out[0] = (float)(*acc * (1.0 / ((double)NROWS * (double)(NROWS - 1))));
}

extern "C" void kernel_launch(void* const* d_in, const int* in_sizes, int n_in,
                              void* d_out, int out_size, void* d_ws, size_t ws_size,
                              hipStream_t stream) {
    const float* q = (const float*)d_in[0];
    const float* k = (const float*)d_in[1];
    float* out = (float*)d_out;

    double* acc = (double*)d_ws;
    uint_t* A   = (uint_t*)((char*)d_ws + 256);                      // 8192*256 bf16 = 4 MB
    uint_t* B   = (uint_t*)((char*)d_ws + 256 + (size_t)NROWS * KTOT * 2);

    norm_kernel<<<NROWS / 4, 256, 0, stream>>>(q, k, A, B, acc);
    gram_kernel<<<NPAIRS, 256, 0, stream>>>((const ushort_t*)A, (const ushort_t*)B, acc);
    finalize_kernel<<<1, 1, 0, stream>>>(acc, out);
}

// Round 3
// 95.536 us; speedup vs baseline: 1.0299x; 1.0064x over previous
//
#include <hip/hip_runtime.h>
#include <hip/hip_bf16.h>

#define NROWS 8192
#define DDIM  128
#define KTOT  256                  // concat K = [Qn | Kn]
#define BM    128                  // tile rows per block side
#define NT    (NROWS / BM)         // 64 tiles per side
#define NPAIRS (NT * (NT + 1) / 2) // 2080 triangular tile pairs
#define BK    64                   // bf16 per K-phase
#define NPH   (KTOT / BK)          // 4 phases
#define ROWB  (KTOT * 2)           // 512 bytes per concat row

typedef unsigned short ushort_t;
typedef unsigned int   uint_t;
typedef __attribute__((ext_vector_type(8))) short  short8;
typedef __attribute__((ext_vector_type(4))) float  floatx4;

#define LDS_PTR(p) ((__attribute__((address_space(3))) void*)(p))
#define GLB_PTR(p) ((const __attribute__((address_space(1))) void*)(p))

// round-to-nearest-even fp32 -> bf16 bits
static __device__ inline ushort_t f2bf(float f) {
    union { float f; uint_t u; } a; a.f = f;
    uint_t u = a.u + 0x7fffu + ((a.u >> 16) & 1u);
    return (ushort_t)(u >> 16);
}

// K1: row-normalize q,k -> bf16; build A=[qn|kn], B=[qn|-kn] (8192 x 256 bf16 each).
__global__ __launch_bounds__(256) void norm_kernel(
    const float* __restrict__ q, const float* __restrict__ k,
    uint_t* __restrict__ A, uint_t* __restrict__ B, double* acc)
{
    if (blockIdx.x == 0 && threadIdx.x == 0) *acc = 0.0;
    int wave = threadIdx.x >> 6;
    int lane = threadIdx.x & 63;
    int row  = blockIdx.x * 4 + wave;   // 2048 blocks x 4 waves = 8192 rows

    uint_t pq, pk;
    {
        const float2* r2 = (const float2*)(q + (size_t)row * DDIM);
        float2 v = r2[lane];
        float ss = v.x * v.x + v.y * v.y;
        #pragma unroll
        for (int o = 32; o > 0; o >>= 1) ss += __shfl_xor(ss, o, 64);
        float inv = rsqrtf(fmaxf(ss, 1e-16f));
        pq = (uint_t)f2bf(v.x * inv) | ((uint_t)f2bf(v.y * inv) << 16);
    }
    {
        const float2* r2 = (const float2*)(k + (size_t)row * DDIM);
        float2 v = r2[lane];
        float ss = v.x * v.x + v.y * v.y;
        #pragma unroll
        for (int o = 32; o > 0; o >>= 1) ss += __shfl_xor(ss, o, 64);
        float inv = rsqrtf(fmaxf(ss, 1e-16f));
        pk = (uint_t)f2bf(v.x * inv) | ((uint_t)f2bf(v.y * inv) << 16);
    }
    size_t rbase = (size_t)row * (KTOT / 2);   // uints per row = 128
    A[rbase + lane]      = pq;
    A[rbase + 64 + lane] = pk;
    B[rbase + lane]      = pq;
    B[rbase + 64 + lane] = pk ^ 0x80008000u;   // negate both bf16 halves
}

// K2: C = A_I . B_J^T (= qsim - ksim) for triangular tile pairs via MFMA;
// accumulate sum C^2 (x2 off-diagonal) into fp64 accumulator.
// NEW: XCD-locality supertiling. 64 tiles -> 16 supergroups of 4. Each XCD
// (blockIdx%8, assuming round-robin dispatch) owns 2 diagonal supertile-pairs
// (10 tile-pairs each) + 15 off-diagonal (16 tile-pairs each) = 260 blocks.
// Concurrent working set per XCD ~3 MB < 4 MB L2.
__global__ __launch_bounds__(256, 3) void gram_kernel(
    const ushort_t* __restrict__ A, const ushort_t* __restrict__ B, double* acc)
{
    __shared__ ushort_t sA[BM * BK];   // 16 KB
    __shared__ ushort_t sB[BM * BK];   // 16 KB
    __shared__ float    wsum[4];

    // ---- XCD-local supertile decode ----
    int x = blockIdx.x & 7;       // XCD id under round-robin dispatch
    int s = blockIdx.x >> 3;      // 0..259 per-XCD slot
    int I, J;
    if (s < 20) {
        // 2 diagonal supergroups per XCD: d = x, x+8; 10 triangular 4x4 pairs each
        int d = x + 8 * (s / 10);
        int w = s % 10;
        int i = 0, len = 4;
        while (w >= len) { w -= len; len--; i++; }
        I = d * 4 + i;
        J = d * 4 + (i + w);
    } else {
        // 15 off-diagonal supertile-pairs per XCD: e = x, x+8, ..., x+112
        int o = s - 20;
        int e = x + 8 * (o / 16);
        int w = o % 16;
        int P = 0, len = 15;
        while (e >= len) { e -= len; len--; P++; }
        int Q = P + 1 + e;
        I = P * 4 + (w >> 2);
        J = Q * 4 + (w & 3);
    }

    int tid  = threadIdx.x;
    int wv   = tid >> 6;
    int l    = tid & 63;
    int m    = l & 15;
    int quad = l >> 4;
    int wr   = (wv >> 1) * 64;
    int wc   = (wv & 1) * 64;

    floatx4 accC[4][4];
    #pragma unroll
    for (int a = 0; a < 4; ++a)
        #pragma unroll
        for (int b = 0; b < 4; ++b)
            accC[a][b] = (floatx4){0.f, 0.f, 0.f, 0.f};

    // staging lane constants: lane l covers row (8*c + l/8) of its wave's 32-row
    // chunk, chunk (l%8) in LDS; logical chunk = (l%8) ^ (row&7)
    int lrow  = l >> 3;                       // 0..7
    int chlog = (l & 7) ^ (lrow & 7);
    const char* gA = (const char*)A + (size_t)(I * BM) * ROWB;
    const char* gB = (const char*)B + (size_t)(J * BM) * ROWB;

    #pragma unroll
    for (int ph = 0; ph < NPH; ++ph) {
        int k0b = ph * BK * 2;   // byte offset within concat row
        #pragma unroll
        for (int c = 0; c < 4; ++c) {
            int r = wv * 32 + c * 8 + lrow;    // local row 0..127
            const char* srcA = gA + (size_t)r * ROWB + k0b + chlog * 16;
            const char* srcB = gB + (size_t)r * ROWB + k0b + chlog * 16;
            __builtin_amdgcn_global_load_lds(GLB_PTR(srcA), LDS_PTR((char*)sA + (wv * 4 + c) * 1024), 16, 0, 0);
            __builtin_amdgcn_global_load_lds(GLB_PTR(srcB), LDS_PTR((char*)sB + (wv * 4 + c) * 1024), 16, 0, 0);
        }
        __syncthreads();

        #pragma unroll
        for (int sb = 0; sb < 2; ++sb) {
            short8 af[4], bf[4];
            #pragma unroll
            for (int t = 0; t < 4; ++t) {
                int ra = wr + t * 16 + m;
                int rb = wc + t * 16 + m;
                int ch = (sb * 4 + quad) ^ (m & 7);       // row&7 == m&7 here
                af[t] = *(const short8*)&sA[ra * 64 + ch * 8];
                bf[t] = *(const short8*)&sB[rb * 64 + ch * 8];
            }
            #pragma unroll
            for (int rt = 0; rt < 4; ++rt)
                #pragma unroll
                for (int ct = 0; ct < 4; ++ct)
                    accC[rt][ct] = __builtin_amdgcn_mfma_f32_16x16x32_bf16(af[rt], bf[ct], accC[rt][ct], 0, 0, 0);
        }
        __syncthreads();
    }

    // epilogue: sum of squares
    float sum = 0.f;
    #pragma unroll
    for (int rt = 0; rt < 4; ++rt)
        #pragma unroll
        for (int ct = 0; ct < 4; ++ct)
            #pragma unroll
            for (int r = 0; r < 4; ++r) {
                float d = accC[rt][ct][r];
                sum += d * d;
            }
    if (I != J) sum *= 2.0f;

    #pragma unroll
    for (int o = 32; o > 0; o >>= 1) sum += __shfl_xor(sum, o, 64);
    if (l == 0) wsum[wv] = sum;
    __syncthreads();
    if (tid == 0) {
        double t = (double)wsum[0] + (double)wsum[1] + (double)wsum[2] + (double)wsum[3];
        atomicAdd(acc, t);
    }
}

// K3: scale and emit scalar
__global__ void finalize_kernel(const double* acc, float* out) {
    out[0] = (float)(*acc * (1.0 / ((double)NROWS * (double)(NROWS - 1))));
}

extern "C" void kernel_launch(void* const* d_in, const int* in_sizes, int n_in,
                              void* d_out, int out_size, void* d_ws, size_t ws_size,
                              hipStream_t stream) {
    const float* q = (const float*)d_in[0];
    const float* k = (const float*)d_in[1];
    float* out = (float*)d_out;

    double* acc = (double*)d_ws;
    uint_t* A   = (uint_t*)((char*)d_ws + 256);                      // 8192*256 bf16 = 4 MB
    uint_t* B   = (uint_t*)((char*)d_ws + 256 + (size_t)NROWS * KTOT * 2);

    norm_kernel<<<NROWS / 4, 256, 0, stream>>>(q, k, A, B, acc);
    gram_kernel<<<NPAIRS, 256, 0, stream>>>((const ushort_t*)A, (const ushort_t*)B, acc);
    finalize_kernel<<<1, 1, 0, stream>>>(acc, out);
}

// Round 4
// 90.900 us; speedup vs baseline: 1.0824x; 1.0510x over previous
//
#include <hip/hip_runtime.h>
#include <hip/hip_bf16.h>

#define NROWS 8192
#define DDIM  128
#define KTOT  256                  // concat K = [Qn | Kn]
#define BM    256                  // tile rows per block side
#define NT    (NROWS / BM)         // 32 tiles per side
#define NPAIRS (NT * (NT + 1) / 2) // 528 triangular tile pairs
#define BK    64                   // bf16 per K-phase
#define NPH   (KTOT / BK)          // 4 phases
#define ROWB  (KTOT * 2)           // 512 bytes per concat row

typedef unsigned short ushort_t;
typedef unsigned int   uint_t;
typedef __attribute__((ext_vector_type(8))) short          short8;
typedef __attribute__((ext_vector_type(8))) unsigned short ushort8;
typedef __attribute__((ext_vector_type(4))) float          floatx4;

#define LDS_PTR(p) ((__attribute__((address_space(3))) void*)(p))
#define GLB_PTR(p) ((const __attribute__((address_space(1))) void*)(p))

// round-to-nearest-even fp32 -> bf16 bits
static __device__ inline ushort_t f2bf(float f) {
    union { float f; uint_t u; } a; a.f = f;
    uint_t u = a.u + 0x7fffu + ((a.u >> 16) & 1u);
    return (ushort_t)(u >> 16);
}

// K1: row-normalize q,k -> bf16 into single concat array G = [qn | kn] (8192 x 256).
__global__ __launch_bounds__(256) void norm_kernel(
    const float* __restrict__ q, const float* __restrict__ k,
    uint_t* __restrict__ G, double* acc)
{
    if (blockIdx.x == 0 && threadIdx.x == 0) *acc = 0.0;
    int wave = threadIdx.x >> 6;
    int lane = threadIdx.x & 63;
    int row  = blockIdx.x * 4 + wave;   // 2048 blocks x 4 waves = 8192 rows

    uint_t pq, pk;
    {
        const float2* r2 = (const float2*)(q + (size_t)row * DDIM);
        float2 v = r2[lane];
        float ss = v.x * v.x + v.y * v.y;
        #pragma unroll
        for (int o = 32; o > 0; o >>= 1) ss += __shfl_xor(ss, o, 64);
        float inv = rsqrtf(fmaxf(ss, 1e-16f));
        pq = (uint_t)f2bf(v.x * inv) | ((uint_t)f2bf(v.y * inv) << 16);
    }
    {
        const float2* r2 = (const float2*)(k + (size_t)row * DDIM);
        float2 v = r2[lane];
        float ss = v.x * v.x + v.y * v.y;
        #pragma unroll
        for (int o = 32; o > 0; o >>= 1) ss += __shfl_xor(ss, o, 64);
        float inv = rsqrtf(fmaxf(ss, 1e-16f));
        pk = (uint_t)f2bf(v.x * inv) | ((uint_t)f2bf(v.y * inv) << 16);
    }
    size_t rbase = (size_t)row * (KTOT / 2);   // uints per row = 128
    G[rbase + lane]      = pq;
    G[rbase + 64 + lane] = pk;
}

// K2: C_IJ = A_I . B_J^T where A = G, B = [Qn | -Kn] (sign folded into B-frags via
// XOR 0x8000 on the Kn-half phases)  =>  C = qsim - ksim.
// 256x256 tile per block, 512 threads (8 waves, 2x4 wave grid, 128 accs/lane).
// Staged bytes: 528 blocks x 256 KB = 138 MB (half of round 3).
__global__ __launch_bounds__(512, 2) void gram_kernel(
    const ushort_t* __restrict__ G, double* acc)
{
    __shared__ ushort_t sA[BM * BK];   // 32 KB
    __shared__ ushort_t sB[BM * BK];   // 32 KB
    __shared__ float    wsum[8];

    // decode triangular pair (I <= J), NT=32
    int rem = blockIdx.x, I = 0, len = NT;
    while (rem >= len) { rem -= len; len--; I++; }
    int J = I + rem;

    int tid  = threadIdx.x;
    int w    = tid >> 6;          // 0..7
    int l    = tid & 63;
    int m    = l & 15;
    int quad = l >> 4;
    int wrow = (w >> 2) * 128;    // 0 or 128
    int wcol = (w & 3) * 64;      // 0,64,128,192

    floatx4 accC[8][4];
    #pragma unroll
    for (int a = 0; a < 8; ++a)
        #pragma unroll
        for (int b = 0; b < 4; ++b)
            accC[a][b] = (floatx4){0.f, 0.f, 0.f, 0.f};

    // staging lane constants: lane l covers row (w*32 + c*8 + l/8), phys chunk (l%8);
    // logical source chunk = (l%8) ^ (row&7) = (l%8) ^ (l/8)
    int lrow  = l >> 3;                 // 0..7
    int chlog = (l & 7) ^ lrow;
    const char* gA = (const char*)G + (size_t)(I * BM) * ROWB;
    const char* gB = (const char*)G + (size_t)(J * BM) * ROWB;

    const ushort8 negmask = {0x8000,0x8000,0x8000,0x8000,0x8000,0x8000,0x8000,0x8000};

    #pragma unroll
    for (int ph = 0; ph < NPH; ++ph) {
        int k0b = ph * BK * 2;          // byte offset within concat row
        #pragma unroll
        for (int c = 0; c < 4; ++c) {
            int r = w * 32 + c * 8 + lrow;      // local row 0..255
            const char* srcA = gA + (size_t)r * ROWB + k0b + chlog * 16;
            const char* srcB = gB + (size_t)r * ROWB + k0b + chlog * 16;
            __builtin_amdgcn_global_load_lds(GLB_PTR(srcA), LDS_PTR((char*)sA + (w * 4 + c) * 1024), 16, 0, 0);
            __builtin_amdgcn_global_load_lds(GLB_PTR(srcB), LDS_PTR((char*)sB + (w * 4 + c) * 1024), 16, 0, 0);
        }
        __syncthreads();

        #pragma unroll
        for (int sb = 0; sb < 2; ++sb) {
            int ch = (sb * 4 + quad) ^ (m & 7);   // row&7 == m&7 for all frag rows
            short8 af[8], bf[4];
            #pragma unroll
            for (int t = 0; t < 8; ++t) {
                int ra = wrow + t * 16 + m;
                af[t] = *(const short8*)&sA[ra * 64 + ch * 8];
            }
            #pragma unroll
            for (int u = 0; u < 4; ++u) {
                int rb = wcol + u * 16 + m;
                short8 v = *(const short8*)&sB[rb * 64 + ch * 8];
                if (ph >= 2) v = (short8)((ushort8)v ^ negmask);   // -Kn half
                bf[u] = v;
            }
            #pragma unroll
            for (int t = 0; t < 8; ++t)
                #pragma unroll
                for (int u = 0; u < 4; ++u)
                    accC[t][u] = __builtin_amdgcn_mfma_f32_16x16x32_bf16(af[t], bf[u], accC[t][u], 0, 0, 0);
        }
        __syncthreads();
    }

    // epilogue: sum of squares
    float sum = 0.f;
    #pragma unroll
    for (int t = 0; t < 8; ++t)
        #pragma unroll
        for (int u = 0; u < 4; ++u)
            #pragma unroll
            for (int r = 0; r < 4; ++r) {
                float d = accC[t][u][r];
                sum += d * d;
            }
    if (I != J) sum *= 2.0f;

    #pragma unroll
    for (int o = 32; o > 0; o >>= 1) sum += __shfl_xor(sum, o, 64);
    if (l == 0) wsum[w] = sum;
    __syncthreads();
    if (tid == 0) {
        double tacc = 0.0;
        #pragma unroll
        for (int i = 0; i < 8; ++i) tacc += (double)wsum[i];
        atomicAdd(acc, tacc);
    }
}

// K3: scale and emit scalar
__global__ void finalize_kernel(const double* acc, float* out) {
    out[0] = (float)(*acc * (1.0 / ((double)NROWS * (double)(NROWS - 1))));
}

extern "C" void kernel_launch(void* const* d_in, const int* in_sizes, int n_in,
                              void* d_out, int out_size, void* d_ws, size_t ws_size,
                              hipStream_t stream) {
    const float* q = (const float*)d_in[0];
    const float* k = (const float*)d_in[1];
    float* out = (float*)d_out;

    double* acc = (double*)d_ws;
    uint_t* G   = (uint_t*)((char*)d_ws + 256);   // 8192 x 256 bf16 = 4 MB

    norm_kernel<<<NROWS / 4, 256, 0, stream>>>(q, k, G, acc);
    gram_kernel<<<NPAIRS, 512, 0, stream>>>((const ushort_t*)G, acc);
    finalize_kernel<<<1, 1, 0, stream>>>(acc, out);
}